// Round 15
// baseline (1146.663 us; speedup 1.0000x reference)
//
#include <hip/hip_runtime.h>
#include <hip/hip_bf16.h>

// ---------------------------------------------------------------------------
// FeatureAggregator: B=8, T=1024, D=2048, E=512, H=8, L=2
// R15: T1 bijective XCD-colocate swizzle on bgemm (20 blocks sharing an
//      A-panel -> one XCD) and cgemm2 (16 y-blocks sharing A -> one XCD).
//      Everything else identical to R14 (1070 us baseline).
// ---------------------------------------------------------------------------

typedef __attribute__((ext_vector_type(4))) float f32x4;
typedef __attribute__((ext_vector_type(8))) short short8;
typedef __attribute__((ext_vector_type(8))) unsigned short ushort8;

__device__ __forceinline__ unsigned short f2bu(float f) {
    __hip_bfloat16 h = __float2bfloat16(f);
    return *reinterpret_cast<unsigned short*>(&h);
}
__device__ __forceinline__ float bu2f(unsigned short u) {
    __hip_bfloat16 h = *reinterpret_cast<__hip_bfloat16*>(&u);
    return __bfloat162float(h);
}

__device__ __forceinline__ void gload16(const void* g, void* l) {
    __builtin_amdgcn_global_load_lds(
        (const __attribute__((address_space(1))) unsigned int*)g,
        (__attribute__((address_space(3))) unsigned int*)l, 16, 0, 0);
}

// fp32 -> bf16 cast
__global__ void cast_kernel(const float* __restrict__ in, unsigned short* __restrict__ out, int n8)
{
    for (int i = blockIdx.x * blockDim.x + threadIdx.x; i < n8; i += gridDim.x * blockDim.x) {
        const float4* p = (const float4*)in + (size_t)i * 2;
        float4 a = p[0], b = p[1];
        ushort8 o;
        o[0] = f2bu(a.x); o[1] = f2bu(a.y); o[2] = f2bu(a.z); o[3] = f2bu(a.w);
        o[4] = f2bu(b.x); o[5] = f2bu(b.y); o[6] = f2bu(b.z); o[7] = f2bu(b.w);
        *(ushort8*)(out + (size_t)i * 8) = o;
    }
}

// Batched weight transform: src (N, K, taps) fp32 -> dst [taps][N][K] bf16
struct WJob { const float* src; unsigned short* dst; int N, K, taps; };
struct WJobs { WJob j[19]; int n; };

__global__ void wtrans_multi(WJobs jobs)
{
    for (int q = 0; q < jobs.n; ++q) {
        const float* __restrict__ src = jobs.j[q].src;
        unsigned short* __restrict__ dst = jobs.j[q].dst;
        const int N = jobs.j[q].N, K = jobs.j[q].K, taps = jobs.j[q].taps;
        const int total = N * K * taps;
        for (int idx = blockIdx.x * blockDim.x + threadIdx.x; idx < total;
             idx += gridDim.x * blockDim.x) {
            int i   = idx % K;
            int rem = idx / K;
            int o   = rem % N;
            int k   = rem / N;
            dst[idx] = f2bu(src[((size_t)o * K + i) * (size_t)taps + k]);
        }
    }
}

// swizzle key: LDS row r's 16B chunk j holds global chunk j ^ SKEY(r)
#define SKEY(r) (((r) >> 2) & 3)

// ---------------------------------------------------------------------------
// Plain 1x1 bf16 MFMA GEMM, double-buffered.  Tile BM_ x 128, BK=32, 4 waves.
// ---------------------------------------------------------------------------
template<int BM_, int EPI>
__global__ __launch_bounds__(256)
void mgemm(const __hip_bfloat16* __restrict__ A, int lda,
           const __hip_bfloat16* __restrict__ Bw, const float* __restrict__ bias,
           float* __restrict__ Cf, __hip_bfloat16* __restrict__ Cb, int ldc,
           int N, int K,
           const float* __restrict__ r1, int ldr, const float* __restrict__ r2)
{
    constexpr int MREP = BM_ / 32;
    __shared__ __align__(16) short As[2][BM_ * 32];
    __shared__ __align__(16) short Bs[2][128 * 32];

    const int tid  = threadIdx.x;
    const int w    = tid >> 6;
    const int lane = tid & 63;
    const int wr   = w >> 1, wc = w & 1;
    const int m_base = blockIdx.x * BM_;
    const int n_base = blockIdx.y * 128;
    const int lrr = lane >> 2;
    const int lj  = lane & 3;

    f32x4 acc[MREP][4];
#pragma unroll
    for (int m = 0; m < MREP; ++m)
#pragma unroll
        for (int n = 0; n < 4; ++n) acc[m][n] = (f32x4){0.f, 0.f, 0.f, 0.f};

    auto stage = [&](int nb, int kc) {
#pragma unroll
        for (int cb = 0; cb < 2; ++cb) {
            const int cc = w + cb * 4;
            const int r  = cc * 16 + lrr;
            const int jc = lj ^ SKEY(r);
            gload16((const void*)(Bw + (size_t)(n_base + r) * K + kc + jc * 8),
                    (void*)&Bs[nb][cc * 512]);
        }
#pragma unroll
        for (int ca = 0; ca < BM_ / 64; ++ca) {
            const int cc = w + ca * 4;
            const int r  = cc * 16 + lrr;
            const int jc = lj ^ SKEY(r);
            gload16((const void*)(A + (size_t)(m_base + r) * lda + kc + jc * 8),
                    (void*)&As[nb][cc * 512]);
        }
    };

    stage(0, 0);
    __syncthreads();
    int cur = 0;
    const int nt = K / 32;
    for (int t = 0; t < nt; ++t) {
        if (t + 1 < nt) stage(cur ^ 1, (t + 1) * 32);

        short8 a[MREP], b[4];
#pragma unroll
        for (int m = 0; m < MREP; ++m) {
            const int i = wr * (BM_ / 2) + m * 16 + (lane & 15);
            a[m] = *(const short8*)&As[cur][i * 32 + (((lane >> 4) ^ SKEY(i)) * 8)];
        }
#pragma unroll
        for (int n = 0; n < 4; ++n) {
            const int r = wc * 64 + n * 16 + (lane & 15);
            b[n] = *(const short8*)&Bs[cur][r * 32 + (((lane >> 4) ^ SKEY(r)) * 8)];
        }
#pragma unroll
        for (int m = 0; m < MREP; ++m)
#pragma unroll
            for (int n = 0; n < 4; ++n)
                acc[m][n] = __builtin_amdgcn_mfma_f32_16x16x32_bf16(a[m], b[n], acc[m][n], 0, 0, 0);

        __syncthreads();
        cur ^= 1;
    }

#pragma unroll
    for (int m = 0; m < MREP; ++m) {
#pragma unroll
        for (int n = 0; n < 4; ++n) {
#pragma unroll
            for (int j = 0; j < 4; ++j) {
                const int row = m_base + wr * (BM_ / 2) + m * 16 + (lane >> 4) * 4 + j;
                const int col = n_base + wc * 64 + n * 16 + (lane & 15);
                float v = acc[m][n][j];
                if (bias) v += bias[col];
                const size_t idx = (size_t)row * ldc + col;
                if (EPI == 1) v = fmaxf(v, 0.f);
                if (EPI == 3) {
                    v += r1[(size_t)row * ldr + col];
                    v = fmaxf(v, 0.f) + r2[(size_t)row * 2048 + col];
                    Cf[idx] = v;
                } else {
                    if (Cf) Cf[idx] = v;
                    if (Cb) Cb[idx] = __float2bfloat16(v);
                }
            }
        }
    }
}

// ---------------------------------------------------------------------------
// Plain GEMM, 256x128 tile, 8 waves (4m x 2n, wave 64x64), double-buffered.
// For wide-N shapes (N>=1536): qkv, ff1, bw3.
// ---------------------------------------------------------------------------
template<int EPI>
__global__ __launch_bounds__(512, 4)
void pgemm(const __hip_bfloat16* __restrict__ A, int lda,
           const __hip_bfloat16* __restrict__ Bw, const float* __restrict__ bias,
           float* __restrict__ Cf, __hip_bfloat16* __restrict__ Cb, int ldc,
           int N, int K,
           const float* __restrict__ r1, int ldr, const float* __restrict__ r2)
{
    __shared__ __align__(16) short As[2][256 * 32];
    __shared__ __align__(16) short Bs[2][128 * 32];

    const int tid  = threadIdx.x;
    const int w    = tid >> 6;
    const int lane = tid & 63;
    const int wr   = w >> 1, wc = w & 1;
    const int m_base = blockIdx.x * 256;
    const int n_base = blockIdx.y * 128;
    const int lrr = lane >> 2;
    const int lj  = lane & 3;

    f32x4 acc[4][4];
#pragma unroll
    for (int m = 0; m < 4; ++m)
#pragma unroll
        for (int n = 0; n < 4; ++n) acc[m][n] = (f32x4){0.f, 0.f, 0.f, 0.f};

    auto stage = [&](int nb, int kc) {
        {
            const int r  = w * 16 + lrr;
            const int jc = lj ^ SKEY(r);
            gload16((const void*)(Bw + (size_t)(n_base + r) * K + kc + jc * 8),
                    (void*)&Bs[nb][w * 512]);
        }
#pragma unroll
        for (int ca = 0; ca < 2; ++ca) {
            const int cc = w + ca * 8;
            const int r  = cc * 16 + lrr;
            const int jc = lj ^ SKEY(r);
            gload16((const void*)(A + (size_t)(m_base + r) * lda + kc + jc * 8),
                    (void*)&As[nb][cc * 512]);
        }
    };

    stage(0, 0);
    __syncthreads();
    int cur = 0;
    const int nt = K / 32;
    for (int t = 0; t < nt; ++t) {
        if (t + 1 < nt) stage(cur ^ 1, (t + 1) * 32);

        short8 a[4], b[4];
#pragma unroll
        for (int m = 0; m < 4; ++m) {
            const int i = wr * 64 + m * 16 + (lane & 15);
            a[m] = *(const short8*)&As[cur][i * 32 + (((lane >> 4) ^ SKEY(i)) * 8)];
        }
#pragma unroll
        for (int n = 0; n < 4; ++n) {
            const int r = wc * 64 + n * 16 + (lane & 15);
            b[n] = *(const short8*)&Bs[cur][r * 32 + (((lane >> 4) ^ SKEY(r)) * 8)];
        }
#pragma unroll
        for (int m = 0; m < 4; ++m)
#pragma unroll
            for (int n = 0; n < 4; ++n)
                acc[m][n] = __builtin_amdgcn_mfma_f32_16x16x32_bf16(a[m], b[n], acc[m][n], 0, 0, 0);

        __syncthreads();
        cur ^= 1;
    }

#pragma unroll
    for (int m = 0; m < 4; ++m) {
#pragma unroll
        for (int n = 0; n < 4; ++n) {
#pragma unroll
            for (int j = 0; j < 4; ++j) {
                const int row = m_base + wr * 64 + m * 16 + (lane >> 4) * 4 + j;
                const int col = n_base + wc * 64 + n * 16 + (lane & 15);
                float v = acc[m][n][j];
                if (bias) v += bias[col];
                const size_t idx = (size_t)row * ldc + col;
                if (EPI == 1) v = fmaxf(v, 0.f);
                if (EPI == 3) {
                    v += r1[(size_t)row * ldr + col];
                    v = fmaxf(v, 0.f) + r2[(size_t)row * 2048 + col];
                    Cf[idx] = v;
                } else {
                    if (Cf) Cf[idx] = v;
                    if (Cb) Cb[idx] = __float2bfloat16(v);
                }
            }
        }
    }
}

// ---------------------------------------------------------------------------
// 128-tile halo conv GEMM, single-buffered (bw2: N=512 small shape).
// ---------------------------------------------------------------------------
template<int NTAPS, int EPI>
__global__ __launch_bounds__(256)
void cgemm(const __hip_bfloat16* __restrict__ A1, const __hip_bfloat16* __restrict__ A2,
           int split, int lda,
           const __hip_bfloat16* __restrict__ Bw, const float* __restrict__ bias,
           float* __restrict__ Cf, __hip_bfloat16* __restrict__ Cb, int ldc,
           int N, int K,
           int o0, int o1, int o2,
           const float* __restrict__ bnp,
           const __hip_bfloat16* __restrict__ zb)
{
    __shared__ __align__(16) short As[144 * 32];
    __shared__ __align__(16) short Bs[NTAPS * 128 * 32];

    const int tid  = threadIdx.x;
    const int w    = tid >> 6;
    const int lane = tid & 63;
    const int wr   = w >> 1, wc = w & 1;
    const int m_base = blockIdx.x * 128;
    const int n_base = blockIdx.y * 128;
    const int tb   = m_base & 1023;
    const int lrr  = lane >> 2;
    const int lj   = lane & 3;

    f32x4 acc[4][4];
#pragma unroll
    for (int m = 0; m < 4; ++m)
#pragma unroll
        for (int n = 0; n < 4; ++n) acc[m][n] = (f32x4){0.f, 0.f, 0.f, 0.f};

    for (int kc = 0; kc < K; kc += 32) {
        __syncthreads();
        for (int c = w; c < 9; c += 4) {
            const int i    = c * 16 + lrr;
            const int jc   = lj ^ SKEY(i);
            const int trow = tb + i - 8;
            const int c0   = kc + jc * 8;
            const void* src;
            if ((unsigned)trow < 1024u) {
                const int g = m_base - 8 + i;
                src = (c0 < split) ? (const void*)(A1 + (size_t)g * lda + c0)
                                   : (const void*)(A2 + (size_t)g * lda + (c0 - split));
            } else {
                src = (const void*)(zb + jc * 8);
            }
            gload16(src, (void*)&As[c * 512]);
        }
        for (int cb = w; cb < NTAPS * 8; cb += 4) {
            const int tap = cb >> 3, sub = cb & 7;
            const int r   = sub * 16 + lrr;
            const int jc  = lj ^ SKEY(r);
            gload16((const void*)(Bw + ((size_t)tap * N + n_base + r) * K + kc + jc * 8),
                    (void*)&Bs[cb * 512]);
        }
        __syncthreads();

#pragma unroll
        for (int tap = 0; tap < NTAPS; ++tap) {
            const int off = (tap == 0) ? o0 : (tap == 1) ? o1 : o2;
            short8 a[4], b[4];
#pragma unroll
            for (int m = 0; m < 4; ++m) {
                const int i = 8 + off + wr * 64 + m * 16 + (lane & 15);
                a[m] = *(const short8*)&As[i * 32 + (((lane >> 4) ^ SKEY(i)) * 8)];
            }
#pragma unroll
            for (int n = 0; n < 4; ++n) {
                const int r = wc * 64 + n * 16 + (lane & 15);
                b[n] = *(const short8*)&Bs[tap * 4096 + r * 32 + (((lane >> 4) ^ SKEY(r)) * 8)];
            }
#pragma unroll
            for (int m = 0; m < 4; ++m)
#pragma unroll
                for (int n = 0; n < 4; ++n)
                    acc[m][n] = __builtin_amdgcn_mfma_f32_16x16x32_bf16(a[m], b[n], acc[m][n], 0, 0, 0);
        }
    }

#pragma unroll
    for (int m = 0; m < 4; ++m) {
#pragma unroll
        for (int n = 0; n < 4; ++n) {
#pragma unroll
            for (int j = 0; j < 4; ++j) {
                const int row = m_base + wr * 64 + m * 16 + (lane >> 4) * 4 + j;
                const int col = n_base + wc * 64 + n * 16 + (lane & 15);
                float v = acc[m][n][j];
                if (bias) v += bias[col];
                const size_t idx = (size_t)row * ldc + col;
                if (EPI == 1) v = fmaxf(v, 0.f);
                if (EPI == 2) {
                    v = fmaxf(v, 0.f);
                    const float g  = bnp[col];
                    const float be = bnp[N + col];
                    const float mu = bnp[2 * N + col];
                    const float va = bnp[3 * N + col];
                    v = g * (v - mu) * rsqrtf(va + 1e-5f) + be;
                }
                if (Cf) Cf[idx] = v;
                if (Cb) Cb[idx] = __float2bfloat16(v);
            }
        }
    }
}

// ---------------------------------------------------------------------------
// 256x128-tile halo conv GEMM, 8 waves — cw6.  XCD-colocated y-blocks:
// grid launched as (512,1); x,y derived so the 16 y-blocks sharing an
// A-panel land on one XCD (bijective: c=L%8, s=L/8, x=c+8*(s>>4), y=s&15).
// ---------------------------------------------------------------------------
template<int NTAPS>
__global__ __launch_bounds__(512, 4)
void cgemm2(const __hip_bfloat16* __restrict__ A1, const __hip_bfloat16* __restrict__ A2,
            int split, int lda,
            const __hip_bfloat16* __restrict__ Bw, const float* __restrict__ bias,
            float* __restrict__ Cf, __hip_bfloat16* __restrict__ Cb, int ldc,
            int N, int K,
            int o0, int o1, int o2,
            const float* __restrict__ bnp,
            const __hip_bfloat16* __restrict__ zb)
{
    __shared__ __align__(16) short As[272 * 32];
    __shared__ __align__(16) short Bs[NTAPS * 128 * 32];

    const int tid  = threadIdx.x;
    const int w    = tid >> 6;
    const int lane = tid & 63;
    const int wr   = w >> 1, wc = w & 1;      // 4 x 2 waves
    const int L    = blockIdx.x;              // 0..511
    const int xcd  = L & 7;
    const int sidx = L >> 3;                  // 0..63
    const int bx   = xcd + 8 * (sidx >> 4);   // 0..31
    const int by   = sidx & 15;               // 0..15
    const int m_base = bx * 256;
    const int n_base = by * 128;
    const int tb   = m_base & 1023;
    const int lrr  = lane >> 2;
    const int lj   = lane & 3;

    f32x4 acc[4][4];
#pragma unroll
    for (int m = 0; m < 4; ++m)
#pragma unroll
        for (int n = 0; n < 4; ++n) acc[m][n] = (f32x4){0.f, 0.f, 0.f, 0.f};

    for (int kc = 0; kc < K; kc += 32) {
        __syncthreads();
        for (int c = w; c < 17; c += 8) {
            const int i    = c * 16 + lrr;
            const int jc   = lj ^ SKEY(i);
            const int trow = tb + i - 8;
            const int c0   = kc + jc * 8;
            const void* src;
            if ((unsigned)trow < 1024u) {
                const int g = m_base - 8 + i;
                src = (c0 < split) ? (const void*)(A1 + (size_t)g * lda + c0)
                                   : (const void*)(A2 + (size_t)g * lda + (c0 - split));
            } else {
                src = (const void*)(zb + jc * 8);
            }
            gload16(src, (void*)&As[c * 512]);
        }
        for (int cb = w; cb < NTAPS * 8; cb += 8) {
            const int tap = cb >> 3, sub = cb & 7;
            const int r   = sub * 16 + lrr;
            const int jc  = lj ^ SKEY(r);
            gload16((const void*)(Bw + ((size_t)tap * N + n_base + r) * K + kc + jc * 8),
                    (void*)&Bs[cb * 512]);
        }
        __syncthreads();

#pragma unroll
        for (int tap = 0; tap < NTAPS; ++tap) {
            const int off = (tap == 0) ? o0 : (tap == 1) ? o1 : o2;
            short8 a[4], b[4];
#pragma unroll
            for (int m = 0; m < 4; ++m) {
                const int i = 8 + off + wr * 64 + m * 16 + (lane & 15);
                a[m] = *(const short8*)&As[i * 32 + (((lane >> 4) ^ SKEY(i)) * 8)];
            }
#pragma unroll
            for (int n = 0; n < 4; ++n) {
                const int r = wc * 64 + n * 16 + (lane & 15);
                b[n] = *(const short8*)&Bs[tap * 4096 + r * 32 + (((lane >> 4) ^ SKEY(r)) * 8)];
            }
#pragma unroll
            for (int m = 0; m < 4; ++m)
#pragma unroll
                for (int n = 0; n < 4; ++n)
                    acc[m][n] = __builtin_amdgcn_mfma_f32_16x16x32_bf16(a[m], b[n], acc[m][n], 0, 0, 0);
        }
    }

#pragma unroll
    for (int m = 0; m < 4; ++m) {
#pragma unroll
        for (int n = 0; n < 4; ++n) {
#pragma unroll
            for (int j = 0; j < 4; ++j) {
                const int row = m_base + wr * 64 + m * 16 + (lane >> 4) * 4 + j;
                const int col = n_base + wc * 64 + n * 16 + (lane & 15);
                float v = acc[m][n][j];
                if (bias) v += bias[col];
                v = fmaxf(v, 0.f);
                const float g  = bnp[col];
                const float be = bnp[N + col];
                const float mu = bnp[2 * N + col];
                const float va = bnp[3 * N + col];
                v = g * (v - mu) * rsqrtf(va + 1e-5f) + be;
                const size_t idx = (size_t)row * ldc + col;
                if (Cf) Cf[idx] = v;
                if (Cb) Cb[idx] = __float2bfloat16(v);
            }
        }
    }
}

// ---------------------------------------------------------------------------
// Fused 5-branch conv (4 dilated + conv5), 256x128 tile, 8 waves.
// Launched as flat grid (640,1,1); (x,y,z) derived so the 20 blocks (4y x 5z)
// sharing an A-panel colocate on one XCD.  Bijective:
//   c=L%8, s=L/8 (0..79), q=s/20 (0..3), r=s%20; x=c+8q, y=r&3, z=r/4.
// ---------------------------------------------------------------------------
struct BrP {
    const __hip_bfloat16* W;
    const float* bias;
    const float* bn;
    __hip_bfloat16* out;
    int ntaps, wti;
    int o0, o1, o2, o3, o4;
};
struct BrPs { BrP p[5]; };

__global__ __launch_bounds__(512, 4)
void bgemm(const __hip_bfloat16* __restrict__ A, BrPs ps,
           const float* __restrict__ wts,
           const __hip_bfloat16* __restrict__ zb)
{
    __shared__ __align__(16) short As[272 * 32];
    __shared__ __align__(16) short Bs[5 * 128 * 32];

    const int tid  = threadIdx.x;
    const int w    = tid >> 6;
    const int lane = tid & 63;
    const int wr   = w >> 1, wc = w & 1;      // 4 x 2 waves
    const int L    = blockIdx.x;              // 0..639
    const int xcd  = L & 7;
    const int sidx = L >> 3;                  // 0..79
    const int q    = sidx / 20;               // 0..3
    const int r20  = sidx % 20;
    const int bx   = xcd + 8 * q;             // 0..31
    const int by   = r20 & 3;                 // 0..3
    const int bz   = r20 >> 2;                // 0..4
    const BrP p    = ps.p[bz];
    const int m_base = bx * 256;
    const int n_base = by * 128;
    const int tb   = m_base & 1023;
    const int lrr  = lane >> 2;
    const int lj   = lane & 3;
    const int ntaps = p.ntaps;

    f32x4 acc[4][4];
#pragma unroll
    for (int m = 0; m < 4; ++m)
#pragma unroll
        for (int n = 0; n < 4; ++n) acc[m][n] = (f32x4){0.f, 0.f, 0.f, 0.f};

    for (int kc = 0; kc < 2048; kc += 32) {
        __syncthreads();
        for (int c = w; c < 17; c += 8) {
            const int i    = c * 16 + lrr;
            const int jc   = lj ^ SKEY(i);
            const int trow = tb + i - 8;
            const void* src;
            if ((unsigned)trow < 1024u)
                src = (const void*)(A + (size_t)(m_base - 8 + i) * 2048 + kc + jc * 8);
            else
                src = (const void*)(zb + jc * 8);
            gload16(src, (void*)&As[c * 512]);
        }
        for (int cb = w; cb < ntaps * 8; cb += 8) {
            const int tap = cb >> 3, sub = cb & 7;
            const int r   = sub * 16 + lrr;
            const int jc  = lj ^ SKEY(r);
            gload16((const void*)(p.W + ((size_t)tap * 512 + n_base + r) * 2048 + kc + jc * 8),
                    (void*)&Bs[cb * 512]);
        }
        __syncthreads();

#pragma unroll 5
        for (int tap = 0; tap < ntaps; ++tap) {
            const int off = (tap == 0) ? p.o0 : (tap == 1) ? p.o1 : (tap == 2) ? p.o2
                          : (tap == 3) ? p.o3 : p.o4;
            short8 a[4], b[4];
#pragma unroll
            for (int m = 0; m < 4; ++m) {
                const int i = 8 + off + wr * 64 + m * 16 + (lane & 15);
                a[m] = *(const short8*)&As[i * 32 + (((lane >> 4) ^ SKEY(i)) * 8)];
            }
#pragma unroll
            for (int n = 0; n < 4; ++n) {
                const int r = wc * 64 + n * 16 + (lane & 15);
                b[n] = *(const short8*)&Bs[tap * 4096 + r * 32 + (((lane >> 4) ^ SKEY(r)) * 8)];
            }
#pragma unroll
            for (int m = 0; m < 4; ++m)
#pragma unroll
                for (int n = 0; n < 4; ++n)
                    acc[m][n] = __builtin_amdgcn_mfma_f32_16x16x32_bf16(a[m], b[n], acc[m][n], 0, 0, 0);
        }
    }

    const float wz = wts[p.wti];
#pragma unroll
    for (int m = 0; m < 4; ++m) {
#pragma unroll
        for (int n = 0; n < 4; ++n) {
#pragma unroll
            for (int j = 0; j < 4; ++j) {
                const int row = m_base + wr * 64 + m * 16 + (lane >> 4) * 4 + j;
                const int col = n_base + wc * 64 + n * 16 + (lane & 15);
                float v = acc[m][n][j];
                if (p.bias) v += p.bias[col];
                v = fmaxf(v, 0.f);
                if (p.bn) {
                    const float g  = p.bn[col];
                    const float be = p.bn[512 + col];
                    const float mu = p.bn[1024 + col];
                    const float va = p.bn[1536 + col];
                    v = (g * (v - mu) * rsqrtf(va + 1e-5f) + be) * wz;
                }
                p.out[(size_t)row * 512 + col] = __float2bfloat16(v);
            }
        }
    }
}

// Sum of 4 pre-weighted bf16 buffers -> bf16
__global__ void bsum_kernel(const unsigned short* __restrict__ b0, const unsigned short* __restrict__ b1,
                            const unsigned short* __restrict__ b2, const unsigned short* __restrict__ b3,
                            unsigned short* __restrict__ o, int n8)
{
    for (int i = blockIdx.x * blockDim.x + threadIdx.x; i < n8; i += gridDim.x * blockDim.x) {
        ushort8 v0 = *(const ushort8*)(b0 + (size_t)i * 8);
        ushort8 v1 = *(const ushort8*)(b1 + (size_t)i * 8);
        ushort8 v2 = *(const ushort8*)(b2 + (size_t)i * 8);
        ushort8 v3 = *(const ushort8*)(b3 + (size_t)i * 8);
        ushort8 r;
#pragma unroll
        for (int e = 0; e < 8; ++e)
            r[e] = f2bu(bu2f(v0[e]) + bu2f(v1[e]) + bu2f(v2[e]) + bu2f(v3[e]));
        *(ushort8*)(o + (size_t)i * 8) = r;
    }
}

// LayerNorm (C=512): x = LN(x + t) * g + b; also writes bf16 copy.
__global__ __launch_bounds__(256)
void ln_kernel(float* __restrict__ x, const float* __restrict__ t,
               const float* __restrict__ g, const float* __restrict__ b,
               __hip_bfloat16* __restrict__ xb, int M)
{
    const int wave = threadIdx.x >> 6;
    const int lane = threadIdx.x & 63;
    const int row  = blockIdx.x * 4 + wave;
    if (row >= M) return;
    float* xr = x + (size_t)row * 512;
    const float* tr = t + (size_t)row * 512;
    float v[8];
    float s = 0.f, s2 = 0.f;
#pragma unroll
    for (int j = 0; j < 8; ++j) {
        float val = xr[lane * 8 + j] + tr[lane * 8 + j];
        v[j] = val; s += val; s2 += val * val;
    }
#pragma unroll
    for (int d = 1; d < 64; d <<= 1) {
        s  += __shfl_xor(s, d, 64);
        s2 += __shfl_xor(s2, d, 64);
    }
    const float mean = s * (1.f / 512.f);
    const float var  = s2 * (1.f / 512.f) - mean * mean;
    const float rstd = rsqrtf(var + 1e-5f);
#pragma unroll
    for (int j = 0; j < 8; ++j) {
        const int c = lane * 8 + j;
        const float o = (v[j] - mean) * rstd * g[c] + b[c];
        xr[c] = o;
        xb[(size_t)row * 512 + c] = __float2bfloat16(o);
    }
}

// ---------------------------------------------------------------------------
// MFMA flash attention (bf16 in/out).  setprio kept (m191: attn-positive).
// ---------------------------------------------------------------------------
__global__ __launch_bounds__(256)
void mattn(const __hip_bfloat16* __restrict__ qkv, __hip_bfloat16* __restrict__ o)
{
    __shared__ __align__(16) short Ks[4096];
    __shared__ __align__(16) short Vt[4096];
    __shared__ __align__(16) short Pl[8192];

    const int tid  = threadIdx.x;
    const int w    = tid >> 6;
    const int lane = tid & 63;
    const int g    = lane >> 4;
    const int li   = lane & 15;
    const int b    = blockIdx.x >> 3;
    const int h    = blockIdx.x & 7;
    const int qb   = blockIdx.y * 128 + w * 32;

    const short* qkvs = (const short*)qkv;

    short8 qf[2][2];
#pragma unroll
    for (int m = 0; m < 2; ++m)
#pragma unroll
        for (int ks = 0; ks < 2; ++ks)
            qf[m][ks] = *(const short8*)(qkvs +
                (size_t)(b * 1024 + qb + m * 16 + li) * 1536 + h * 64 + ks * 32 + g * 8);

    f32x4 Oa[2][4];
    float mr[2][4], lr[2][4];
#pragma unroll
    for (int m = 0; m < 2; ++m)
#pragma unroll
        for (int j = 0; j < 4; ++j) { mr[m][j] = -1e30f; lr[m][j] = 0.f; }
#pragma unroll
    for (int m = 0; m < 2; ++m)
#pragma unroll
        for (int n = 0; n < 4; ++n) Oa[m][n] = (f32x4){0.f, 0.f, 0.f, 0.f};

    const int sr = tid >> 2;
    const int sc = (tid & 3) * 16;

    for (int kt = 0; kt < 16; ++kt) {
        __syncthreads();
        const short* kr = qkvs + (size_t)(b * 1024 + kt * 64 + sr) * 1536 + 512 + h * 64 + sc;
        short8 k0 = *(const short8*)kr;
        short8 k1 = *(const short8*)(kr + 8);
        short8 v0 = *(const short8*)(kr + 512);
        short8 v1 = *(const short8*)(kr + 520);
        const int swr = (sr & 7) << 4;
        *(short8*)&Ks[(sr * 128 + ((sc * 2) ^ swr)) >> 1] = k0;
        *(short8*)&Ks[(sr * 128 + ((sc * 2 + 16) ^ swr)) >> 1] = k1;
#pragma unroll
        for (int e = 0; e < 8; ++e) {
            const int d = sc + e;
            Vt[(d * 128 + ((sr * 2) ^ ((d & 7) << 4))) >> 1] = v0[e];
        }
#pragma unroll
        for (int e = 0; e < 8; ++e) {
            const int d = sc + 8 + e;
            Vt[(d * 128 + ((sr * 2) ^ ((d & 7) << 4))) >> 1] = v1[e];
        }
        __syncthreads();

        short8 kf[4][2], vf[4][2];
#pragma unroll
        for (int n = 0; n < 4; ++n) {
            const int r  = n * 16 + li;
            const int sw = (r & 7) << 4;
#pragma unroll
            for (int ks = 0; ks < 2; ++ks) {
                const int cb = ks * 64 + g * 16;
                kf[n][ks] = *(const short8*)&Ks[(r * 128 + (cb ^ sw)) >> 1];
                vf[n][ks] = *(const short8*)&Vt[(r * 128 + (cb ^ sw)) >> 1];
            }
        }

        f32x4 s[2][4];
#pragma unroll
        for (int m = 0; m < 2; ++m)
#pragma unroll
            for (int n = 0; n < 4; ++n) s[m][n] = (f32x4){0.f, 0.f, 0.f, 0.f};
        __builtin_amdgcn_s_setprio(1);
#pragma unroll
        for (int m = 0; m < 2; ++m)
#pragma unroll
            for (int n = 0; n < 4; ++n)
#pragma unroll
                for (int ks = 0; ks < 2; ++ks)
                    s[m][n] = __builtin_amdgcn_mfma_f32_16x16x32_bf16(qf[m][ks], kf[n][ks], s[m][n], 0, 0, 0);
        __builtin_amdgcn_s_setprio(0);

#pragma unroll
        for (int m = 0; m < 2; ++m) {
            float cc[4];
#pragma unroll
            for (int j = 0; j < 4; ++j) {
                float rm = fmaxf(fmaxf(s[m][0][j], s[m][1][j]), fmaxf(s[m][2][j], s[m][3][j]));
                rm *= 0.125f;
#pragma unroll
                for (int d = 1; d < 16; d <<= 1) rm = fmaxf(rm, __shfl_xor(rm, d, 64));
                const float mn = fmaxf(mr[m][j], rm);
                cc[j] = __expf(mr[m][j] - mn);
                mr[m][j] = mn;
            }
            float rs[4] = {0.f, 0.f, 0.f, 0.f};
#pragma unroll
            for (int n = 0; n < 4; ++n)
#pragma unroll
                for (int j = 0; j < 4; ++j) {
                    const float pv = __expf(s[m][n][j] * 0.125f - mr[m][j]);
                    rs[j] += pv;
                    const int r  = m * 16 + g * 4 + j;
                    const int cb = (n * 16 + li) * 2;
                    Pl[(w * 4096 + r * 128 + (cb ^ ((r & 7) << 4))) >> 1] = (short)f2bu(pv);
                }
#pragma unroll
            for (int j = 0; j < 4; ++j) {
#pragma unroll
                for (int d = 1; d < 16; d <<= 1) rs[j] += __shfl_xor(rs[j], d, 64);
                lr[m][j] = lr[m][j] * cc[j] + rs[j];
#pragma unroll
                for (int n = 0; n < 4; ++n) Oa[m][n][j] *= cc[j];
            }
        }
        __syncthreads();

        short8 pa[2][2];
#pragma unroll
        for (int m = 0; m < 2; ++m) {
            const int r  = m * 16 + li;
            const int sw = (r & 7) << 4;
#pragma unroll
            for (int ks = 0; ks < 2; ++ks) {
                const int cb = ks * 64 + g * 16;
                pa[m][ks] = *(const short8*)&Pl[(w * 4096 + r * 128 + (cb ^ sw)) >> 1];
            }
        }
        __builtin_amdgcn_s_setprio(1);
#pragma unroll
        for (int m = 0; m < 2; ++m)
#pragma unroll
            for (int n = 0; n < 4; ++n)
#pragma unroll
                for (int ks = 0; ks < 2; ++ks)
                    Oa[m][n] = __builtin_amdgcn_mfma_f32_16x16x32_bf16(pa[m][ks], vf[n][ks], Oa[m][n], 0, 0, 0);
        __builtin_amdgcn_s_setprio(0);
    }

#pragma unroll
    for (int m = 0; m < 2; ++m)
#pragma unroll
        for (int j = 0; j < 4; ++j) {
            const float inv = 1.f / lr[m][j];
            const size_t row = (size_t)(b * 1024 + qb + m * 16 + g * 4 + j);
#pragma unroll
            for (int n = 0; n < 4; ++n)
                o[row * 512 + h * 64 + n * 16 + li] = __float2bfloat16(Oa[m][n][j] * inv);
        }
}

// ---------------------------------------------------------------------------

extern "C" void kernel_launch(void* const* d_in, const int* in_sizes, int n_in,
                              void* d_out, int out_size, void* d_ws, size_t ws_size,
                              hipStream_t stream)
{
    const float* x       = (const float*)d_in[0];
    const float* wts     = (const float*)d_in[1];
    const float* cw1     = (const float*)d_in[2];
    const float* cb1     = (const float*)d_in[3];
    const float* bn1     = (const float*)d_in[4];
    const float* cw2     = (const float*)d_in[5];
    const float* cb2     = (const float*)d_in[6];
    const float* bn2     = (const float*)d_in[7];
    const float* cw3     = (const float*)d_in[8];
    const float* cb3     = (const float*)d_in[9];
    const float* bn3     = (const float*)d_in[10];
    const float* cw4     = (const float*)d_in[11];
    const float* cb4     = (const float*)d_in[12];
    const float* bn4     = (const float*)d_in[13];
    const float* cw5     = (const float*)d_in[14];
    const float* tcw_in  = (const float*)d_in[15];
    const float* tcb_in  = (const float*)d_in[16];
    const float* t_in_w  = (const float*)d_in[17];
    const float* t_in_b  = (const float*)d_in[18];
    const float* t_out_w = (const float*)d_in[19];
    const float* t_out_b = (const float*)d_in[20];
    const float* ln1_g   = (const float*)d_in[21];
    const float* ln1_b   = (const float*)d_in[22];
    const float* ff_w1   = (const float*)d_in[23];
    const float* ff_b1   = (const float*)d_in[24];
    const float* ff_w2   = (const float*)d_in[25];
    const float* ff_b2   = (const float*)d_in[26];
    const float* ln2_g   = (const float*)d_in[27];
    const float* ln2_b   = (const float*)d_in[28];
    const float* tcw_out = (const float*)d_in[29];
    const float* tcb_out = (const float*)d_in[30];
    const float* cw6     = (const float*)d_in[31];
    const float* bn6     = (const float*)d_in[32];
    const float* bw1     = (const float*)d_in[33];
    const float* bb1     = (const float*)d_in[34];
    const float* bw2     = (const float*)d_in[35];
    const float* bb2     = (const float*)d_in[36];
    const float* bw3     = (const float*)d_in[37];
    const float* bb3     = (const float*)d_in[38];
    float* out = (float*)d_out;

    // -------- workspace map --------
    const size_t HMB = 524288;
    char* ws = (char*)d_ws;
    auto BF = [&](double mb) { return (__hip_bfloat16*)(ws + (size_t)(mb * 2) * HMB); };
    auto FP = [&](double mb) { return (float*)(ws + (size_t)(mb * 2) * HMB); };

    __hip_bfloat16* xb    = BF(0);       // 0-32    x bf16; dead after bgemm
    float*          h7    = FP(0);       // 0-64    cw6 out fp32 (late phase)
    __hip_bfloat16* bigqb = BF(32);      // 32-56   qkv bf16 (transformer)
    __hip_bfloat16* wc1   = BF(32);      // 32-38.5 early conv weights (dead pre-qkv)
    __hip_bfloat16* wc2   = BF(39);      // 39-45.5
    __hip_bfloat16* wc3   = BF(46);      // 46-52.5
    __hip_bfloat16* wc4   = BF(53);      // 53-63.5
    __hip_bfloat16* wc5   = BF(64);      // 64-66.1
    __hip_bfloat16* wti0  = BF(66.5);
    __hip_bfloat16* wti1  = BF(68);
    __hip_bfloat16* wto0  = BF(69.5);
    __hip_bfloat16* wto1  = BF(70);
    __hip_bfloat16* wf10  = BF(70.5);
    __hip_bfloat16* wf11  = BF(72.5);
    __hip_bfloat16* wf20  = BF(74.5);
    __hip_bfloat16* wf21  = BF(76.5);
    __hip_bfloat16* wtci  = BF(78.5);
    __hip_bfloat16* wtco  = BF(79);
    __hip_bfloat16* bigb  = BF(80);      // 80-112  ff hidden bf16
    __hip_bfloat16* h7b   = BF(80);      // 80-112  h7 bf16 (after ff done)
    __hip_bfloat16* br0   = BF(112);     // branch outputs bf16
    __hip_bfloat16* br1   = BF(120);
    __hip_bfloat16* br2   = BF(128);
    __hip_bfloat16* br3   = BF(136);
    float*          tmp   = FP(112);     // LN residual fp32 (after bsum)
    float*          xtf   = FP(128);     // transformer fp32 stream (after bsum)
    __hip_bfloat16* outdb = BF(144);     // branch sum; later bw1 out
    __hip_bfloat16* wc6   = BF(152);     // 152-164.6
    __hip_bfloat16* wtb1  = BF(165);     // 165-167
    __hip_bfloat16* wtb2  = BF(167.5);   // 167.5-169  (3-tap = 1.5 MB)
    __hip_bfloat16* wtb3  = BF(169);     // 169-171
    __hip_bfloat16* tmpb  = BF(171);     // conv5 out / attn out / bw2 out
    __hip_bfloat16* atnb  = BF(171);
    __hip_bfloat16* xtfb  = BF(179);
    __hip_bfloat16* zb    = BF(188);     // zero mask row

    const int M = 8192;
    dim3 blk(256);
    dim3 blk2(512);

    auto mg = [&](int bm, int epi, const __hip_bfloat16* A, int lda,
                  const __hip_bfloat16* Bw, const float* bias,
                  float* Cf, __hip_bfloat16* Cb, int ldc, int N, int K,
                  const float* r1, int ldr, const float* r2) {
        dim3 grid(M / bm, N / 128);
#define LAU(BMV, EPIV) mgemm<BMV, EPIV><<<grid, blk, 0, stream>>>(A, lda, Bw, bias, Cf, Cb, ldc, N, K, r1, ldr, r2)
        if (bm == 64) {
            switch (epi) { case 0: LAU(64, 0); break; case 1: LAU(64, 1); break;
                           default: LAU(64, 3); }
        } else {
            switch (epi) { case 0: LAU(128, 0); break; case 1: LAU(128, 1); break;
                           default: LAU(128, 3); }
        }
#undef LAU
    };

    auto pg = [&](int epi, const __hip_bfloat16* A, int lda,
                  const __hip_bfloat16* Bw, const float* bias,
                  float* Cf, __hip_bfloat16* Cb, int ldc, int N, int K,
                  const float* r1, int ldr, const float* r2) {
        dim3 grid(M / 256, N / 128);
        switch (epi) {
        case 0: pgemm<0><<<grid, blk2, 0, stream>>>(A, lda, Bw, bias, Cf, Cb, ldc, N, K, r1, ldr, r2); break;
        case 1: pgemm<1><<<grid, blk2, 0, stream>>>(A, lda, Bw, bias, Cf, Cb, ldc, N, K, r1, ldr, r2); break;
        default: pgemm<3><<<grid, blk2, 0, stream>>>(A, lda, Bw, bias, Cf, Cb, ldc, N, K, r1, ldr, r2); break;
        }
    };

    // ---- prologue ----
    hipMemsetAsync(zb, 0, 8192, stream);
    cast_kernel<<<dim3(2048), blk, 0, stream>>>(x, (unsigned short*)xb, M * 2048 / 8);

    WJobs jobs{};
    jobs.n = 19;
    jobs.j[0]  = {cw1,                   (unsigned short*)wc1, 512, 2048, 3};
    jobs.j[1]  = {cw2,                   (unsigned short*)wc2, 512, 2048, 3};
    jobs.j[2]  = {cw3,                   (unsigned short*)wc3, 512, 2048, 3};
    jobs.j[3]  = {cw4,                   (unsigned short*)wc4, 512, 2048, 5};
    jobs.j[4]  = {cw5,                   (unsigned short*)wc5, 512, 2048, 1};
    jobs.j[5]  = {t_in_w,                (unsigned short*)wti0, 1536, 512, 1};
    jobs.j[6]  = {t_in_w + 1536 * 512,   (unsigned short*)wti1, 1536, 512, 1};
    jobs.j[7]  = {t_out_w,               (unsigned short*)wto0, 512, 512, 1};
    jobs.j[8]  = {t_out_w + 512 * 512,   (unsigned short*)wto1, 512, 512, 1};
    jobs.j[9]  = {ff_w1,                 (unsigned short*)wf10, 2048, 512, 1};
    jobs.j[10] = {ff_w1 + 2048 * 512,    (unsigned short*)wf11, 2048, 512, 1};
    jobs.j[11] = {ff_w2,                 (unsigned short*)wf20, 512, 2048, 1};
    jobs.j[12] = {ff_w2 + 512 * 2048,    (unsigned short*)wf21, 512, 2048, 1};
    jobs.j[13] = {tcw_in,                (unsigned short*)wtci, 512, 512, 1};
    jobs.j[14] = {tcw_out,               (unsigned short*)wtco, 512, 512, 1};
    jobs.j[15] = {cw6,                   (unsigned short*)wc6, 2048, 1024, 3};
    jobs.j[16] = {bw1,                   (unsigned short*)wtb1, 512, 2048, 1};
    jobs.j[17] = {bw2,                   (unsigned short*)wtb2, 512, 512, 3};
    jobs.j[18] = {bw3,                   (unsigned short*)wtb3, 2048, 512, 1};
    wtrans_multi<<<dim3(2048), blk, 0, stream>>>(jobs);

    // ---- fused 5-branch convs (4 dilated + conv5), single flat launch ----
    BrPs bp{};
    bp.p[0] = {wc1, cb1, bn1, br0, 3, 0, -1, 0, 1, 0, 0};
    bp.p[1] = {wc2, cb2, bn2, br1, 3, 1, -2, 0, 2, 0, 0};
    bp.p[2] = {wc3, cb3, bn3, br2, 3, 2, -4, 0, 4, 0, 0};
    bp.p[3] = {wc4, cb4, bn4, br3, 5, 3, -8, -4, 0, 4, 8};
    bp.p[4] = {wc5, nullptr, nullptr, tmpb, 1, 0, 0, 0, 0, 0, 0};
    bgemm<<<dim3(640), blk2, 0, stream>>>(xb, bp, wts, zb);
    bsum_kernel<<<dim3(2048), blk, 0, stream>>>((const unsigned short*)br0, (const unsigned short*)br1,
                                                (const unsigned short*)br2, (const unsigned short*)br3,
                                                (unsigned short*)outdb, M * 512 / 8);

    // ---- tcw_in -> xtf (+xtfb) ----
    mg(64, 0, tmpb, 512, wtci, tcb_in, xtf, xtfb, 512, 512, 512, nullptr, 0, nullptr);

    // ---- transformer layers ----
    for (int l = 0; l < 2; ++l) {
        const __hip_bfloat16* wi = l ? wti1 : wti0;
        const __hip_bfloat16* wo = l ? wto1 : wto0;
        const __hip_bfloat16* w1 = l ? wf11 : wf10;
        const __hip_bfloat16* w2 = l ? wf21 : wf20;
        pg(0, xtfb, 512, wi, t_in_b + l * 1536, nullptr, bigqb, 1536, 1536, 512,
           nullptr, 0, nullptr);
        mattn<<<dim3(64, 8), blk, 0, stream>>>(bigqb, atnb);
        mg(64, 0, atnb, 512, wo, t_out_b + l * 512, tmp, nullptr, 512, 512, 512,
           nullptr, 0, nullptr);
        ln_kernel<<<dim3(M / 4), blk, 0, stream>>>(xtf, tmp, ln1_g + l * 512, ln1_b + l * 512, xtfb, M);
        pg(1, xtfb, 512, w1, ff_b1 + l * 2048, nullptr, bigb, 2048, 2048, 512,
           nullptr, 0, nullptr);
        mg(64, 0, bigb, 2048, w2, ff_b2 + l * 512, tmp, nullptr, 512, 512, 2048,
           nullptr, 0, nullptr);
        ln_kernel<<<dim3(M / 4), blk, 0, stream>>>(xtf, tmp, ln2_g + l * 512, ln2_b + l * 512, xtfb, M);
    }

    // ---- tcw_out -> atnb (bf16 only) ----
    mg(64, 0, xtfb, 512, wtco, tcb_out, nullptr, atnb, 512, 512, 512, nullptr, 0, nullptr);

    // ---- cw6: concat(outdb, atnb) k=3 -> BN6 -> h7 (fp32 + bf16), flat 512 grid ----
    cgemm2<3><<<dim3(512), blk2, 0, stream>>>(outdb, atnb, 512, 512, wc6, nullptr,
        h7, h7b, 2048, 2048, 1024, -1, 0, 1, bn6, zb);

    // ---- bottleneck ----
    mg(64, 1, h7b, 2048, wtb1, bb1, nullptr, outdb, 512, 512, 2048, nullptr, 0, nullptr);
    cgemm<3, 1><<<dim3(M / 128, 4), blk, 0, stream>>>(outdb, outdb, 4096, 512, wtb2, bb2,
        nullptr, tmpb, 512, 512, 512, -1, 0, 1, nullptr, zb);
    pg(3, tmpb, 512, wtb3, bb3, out, nullptr, 2048, 2048, 512, h7, 2048, x);

    (void)in_sizes; (void)n_in; (void)out_size; (void)ws_size;
}

// Round 16
// 1069.450 us; speedup vs baseline: 1.0722x; 1.0722x over previous
//
#include <hip/hip_runtime.h>
#include <hip/hip_bf16.h>

// ---------------------------------------------------------------------------
// FeatureAggregator: B=8, T=1024, D=2048, E=512, H=8, L=2
// R16: exact revert to R14 (best verified config, 1069.8 us).  R15's XCD
//      swizzle anti-colocated A-panel sharers (FETCH 171->348 MB) -> dropped.
// ---------------------------------------------------------------------------

typedef __attribute__((ext_vector_type(4))) float f32x4;
typedef __attribute__((ext_vector_type(8))) short short8;
typedef __attribute__((ext_vector_type(8))) unsigned short ushort8;

__device__ __forceinline__ unsigned short f2bu(float f) {
    __hip_bfloat16 h = __float2bfloat16(f);
    return *reinterpret_cast<unsigned short*>(&h);
}
__device__ __forceinline__ float bu2f(unsigned short u) {
    __hip_bfloat16 h = *reinterpret_cast<__hip_bfloat16*>(&u);
    return __bfloat162float(h);
}

__device__ __forceinline__ void gload16(const void* g, void* l) {
    __builtin_amdgcn_global_load_lds(
        (const __attribute__((address_space(1))) unsigned int*)g,
        (__attribute__((address_space(3))) unsigned int*)l, 16, 0, 0);
}

// fp32 -> bf16 cast
__global__ void cast_kernel(const float* __restrict__ in, unsigned short* __restrict__ out, int n8)
{
    for (int i = blockIdx.x * blockDim.x + threadIdx.x; i < n8; i += gridDim.x * blockDim.x) {
        const float4* p = (const float4*)in + (size_t)i * 2;
        float4 a = p[0], b = p[1];
        ushort8 o;
        o[0] = f2bu(a.x); o[1] = f2bu(a.y); o[2] = f2bu(a.z); o[3] = f2bu(a.w);
        o[4] = f2bu(b.x); o[5] = f2bu(b.y); o[6] = f2bu(b.z); o[7] = f2bu(b.w);
        *(ushort8*)(out + (size_t)i * 8) = o;
    }
}

// Batched weight transform: src (N, K, taps) fp32 -> dst [taps][N][K] bf16
struct WJob { const float* src; unsigned short* dst; int N, K, taps; };
struct WJobs { WJob j[19]; int n; };

__global__ void wtrans_multi(WJobs jobs)
{
    for (int q = 0; q < jobs.n; ++q) {
        const float* __restrict__ src = jobs.j[q].src;
        unsigned short* __restrict__ dst = jobs.j[q].dst;
        const int N = jobs.j[q].N, K = jobs.j[q].K, taps = jobs.j[q].taps;
        const int total = N * K * taps;
        for (int idx = blockIdx.x * blockDim.x + threadIdx.x; idx < total;
             idx += gridDim.x * blockDim.x) {
            int i   = idx % K;
            int rem = idx / K;
            int o   = rem % N;
            int k   = rem / N;
            dst[idx] = f2bu(src[((size_t)o * K + i) * (size_t)taps + k]);
        }
    }
}

// swizzle key: LDS row r's 16B chunk j holds global chunk j ^ SKEY(r)
#define SKEY(r) (((r) >> 2) & 3)

// ---------------------------------------------------------------------------
// Plain 1x1 bf16 MFMA GEMM, double-buffered.  Tile BM_ x 128, BK=32, 4 waves.
// ---------------------------------------------------------------------------
template<int BM_, int EPI>
__global__ __launch_bounds__(256)
void mgemm(const __hip_bfloat16* __restrict__ A, int lda,
           const __hip_bfloat16* __restrict__ Bw, const float* __restrict__ bias,
           float* __restrict__ Cf, __hip_bfloat16* __restrict__ Cb, int ldc,
           int N, int K,
           const float* __restrict__ r1, int ldr, const float* __restrict__ r2)
{
    constexpr int MREP = BM_ / 32;
    __shared__ __align__(16) short As[2][BM_ * 32];
    __shared__ __align__(16) short Bs[2][128 * 32];

    const int tid  = threadIdx.x;
    const int w    = tid >> 6;
    const int lane = tid & 63;
    const int wr   = w >> 1, wc = w & 1;
    const int m_base = blockIdx.x * BM_;
    const int n_base = blockIdx.y * 128;
    const int lrr = lane >> 2;
    const int lj  = lane & 3;

    f32x4 acc[MREP][4];
#pragma unroll
    for (int m = 0; m < MREP; ++m)
#pragma unroll
        for (int n = 0; n < 4; ++n) acc[m][n] = (f32x4){0.f, 0.f, 0.f, 0.f};

    auto stage = [&](int nb, int kc) {
#pragma unroll
        for (int cb = 0; cb < 2; ++cb) {
            const int cc = w + cb * 4;
            const int r  = cc * 16 + lrr;
            const int jc = lj ^ SKEY(r);
            gload16((const void*)(Bw + (size_t)(n_base + r) * K + kc + jc * 8),
                    (void*)&Bs[nb][cc * 512]);
        }
#pragma unroll
        for (int ca = 0; ca < BM_ / 64; ++ca) {
            const int cc = w + ca * 4;
            const int r  = cc * 16 + lrr;
            const int jc = lj ^ SKEY(r);
            gload16((const void*)(A + (size_t)(m_base + r) * lda + kc + jc * 8),
                    (void*)&As[nb][cc * 512]);
        }
    };

    stage(0, 0);
    __syncthreads();
    int cur = 0;
    const int nt = K / 32;
    for (int t = 0; t < nt; ++t) {
        if (t + 1 < nt) stage(cur ^ 1, (t + 1) * 32);

        short8 a[MREP], b[4];
#pragma unroll
        for (int m = 0; m < MREP; ++m) {
            const int i = wr * (BM_ / 2) + m * 16 + (lane & 15);
            a[m] = *(const short8*)&As[cur][i * 32 + (((lane >> 4) ^ SKEY(i)) * 8)];
        }
#pragma unroll
        for (int n = 0; n < 4; ++n) {
            const int r = wc * 64 + n * 16 + (lane & 15);
            b[n] = *(const short8*)&Bs[cur][r * 32 + (((lane >> 4) ^ SKEY(r)) * 8)];
        }
#pragma unroll
        for (int m = 0; m < MREP; ++m)
#pragma unroll
            for (int n = 0; n < 4; ++n)
                acc[m][n] = __builtin_amdgcn_mfma_f32_16x16x32_bf16(a[m], b[n], acc[m][n], 0, 0, 0);

        __syncthreads();
        cur ^= 1;
    }

#pragma unroll
    for (int m = 0; m < MREP; ++m) {
#pragma unroll
        for (int n = 0; n < 4; ++n) {
#pragma unroll
            for (int j = 0; j < 4; ++j) {
                const int row = m_base + wr * (BM_ / 2) + m * 16 + (lane >> 4) * 4 + j;
                const int col = n_base + wc * 64 + n * 16 + (lane & 15);
                float v = acc[m][n][j];
                if (bias) v += bias[col];
                const size_t idx = (size_t)row * ldc + col;
                if (EPI == 1) v = fmaxf(v, 0.f);
                if (EPI == 3) {
                    v += r1[(size_t)row * ldr + col];
                    v = fmaxf(v, 0.f) + r2[(size_t)row * 2048 + col];
                    Cf[idx] = v;
                } else {
                    if (Cf) Cf[idx] = v;
                    if (Cb) Cb[idx] = __float2bfloat16(v);
                }
            }
        }
    }
}

// ---------------------------------------------------------------------------
// Plain GEMM, 256x128 tile, 8 waves (4m x 2n, wave 64x64), double-buffered.
// For wide-N shapes (N>=1536): qkv, ff1, bw3.
// ---------------------------------------------------------------------------
template<int EPI>
__global__ __launch_bounds__(512, 4)
void pgemm(const __hip_bfloat16* __restrict__ A, int lda,
           const __hip_bfloat16* __restrict__ Bw, const float* __restrict__ bias,
           float* __restrict__ Cf, __hip_bfloat16* __restrict__ Cb, int ldc,
           int N, int K,
           const float* __restrict__ r1, int ldr, const float* __restrict__ r2)
{
    __shared__ __align__(16) short As[2][256 * 32];
    __shared__ __align__(16) short Bs[2][128 * 32];

    const int tid  = threadIdx.x;
    const int w    = tid >> 6;
    const int lane = tid & 63;
    const int wr   = w >> 1, wc = w & 1;
    const int m_base = blockIdx.x * 256;
    const int n_base = blockIdx.y * 128;
    const int lrr = lane >> 2;
    const int lj  = lane & 3;

    f32x4 acc[4][4];
#pragma unroll
    for (int m = 0; m < 4; ++m)
#pragma unroll
        for (int n = 0; n < 4; ++n) acc[m][n] = (f32x4){0.f, 0.f, 0.f, 0.f};

    auto stage = [&](int nb, int kc) {
        {
            const int r  = w * 16 + lrr;
            const int jc = lj ^ SKEY(r);
            gload16((const void*)(Bw + (size_t)(n_base + r) * K + kc + jc * 8),
                    (void*)&Bs[nb][w * 512]);
        }
#pragma unroll
        for (int ca = 0; ca < 2; ++ca) {
            const int cc = w + ca * 8;
            const int r  = cc * 16 + lrr;
            const int jc = lj ^ SKEY(r);
            gload16((const void*)(A + (size_t)(m_base + r) * lda + kc + jc * 8),
                    (void*)&As[nb][cc * 512]);
        }
    };

    stage(0, 0);
    __syncthreads();
    int cur = 0;
    const int nt = K / 32;
    for (int t = 0; t < nt; ++t) {
        if (t + 1 < nt) stage(cur ^ 1, (t + 1) * 32);

        short8 a[4], b[4];
#pragma unroll
        for (int m = 0; m < 4; ++m) {
            const int i = wr * 64 + m * 16 + (lane & 15);
            a[m] = *(const short8*)&As[cur][i * 32 + (((lane >> 4) ^ SKEY(i)) * 8)];
        }
#pragma unroll
        for (int n = 0; n < 4; ++n) {
            const int r = wc * 64 + n * 16 + (lane & 15);
            b[n] = *(const short8*)&Bs[cur][r * 32 + (((lane >> 4) ^ SKEY(r)) * 8)];
        }
#pragma unroll
        for (int m = 0; m < 4; ++m)
#pragma unroll
            for (int n = 0; n < 4; ++n)
                acc[m][n] = __builtin_amdgcn_mfma_f32_16x16x32_bf16(a[m], b[n], acc[m][n], 0, 0, 0);

        __syncthreads();
        cur ^= 1;
    }

#pragma unroll
    for (int m = 0; m < 4; ++m) {
#pragma unroll
        for (int n = 0; n < 4; ++n) {
#pragma unroll
            for (int j = 0; j < 4; ++j) {
                const int row = m_base + wr * 64 + m * 16 + (lane >> 4) * 4 + j;
                const int col = n_base + wc * 64 + n * 16 + (lane & 15);
                float v = acc[m][n][j];
                if (bias) v += bias[col];
                const size_t idx = (size_t)row * ldc + col;
                if (EPI == 1) v = fmaxf(v, 0.f);
                if (EPI == 3) {
                    v += r1[(size_t)row * ldr + col];
                    v = fmaxf(v, 0.f) + r2[(size_t)row * 2048 + col];
                    Cf[idx] = v;
                } else {
                    if (Cf) Cf[idx] = v;
                    if (Cb) Cb[idx] = __float2bfloat16(v);
                }
            }
        }
    }
}

// ---------------------------------------------------------------------------
// 128-tile halo conv GEMM, single-buffered (bw2: N=512 small shape).
// ---------------------------------------------------------------------------
template<int NTAPS, int EPI>
__global__ __launch_bounds__(256)
void cgemm(const __hip_bfloat16* __restrict__ A1, const __hip_bfloat16* __restrict__ A2,
           int split, int lda,
           const __hip_bfloat16* __restrict__ Bw, const float* __restrict__ bias,
           float* __restrict__ Cf, __hip_bfloat16* __restrict__ Cb, int ldc,
           int N, int K,
           int o0, int o1, int o2,
           const float* __restrict__ bnp,
           const __hip_bfloat16* __restrict__ zb)
{
    __shared__ __align__(16) short As[144 * 32];
    __shared__ __align__(16) short Bs[NTAPS * 128 * 32];

    const int tid  = threadIdx.x;
    const int w    = tid >> 6;
    const int lane = tid & 63;
    const int wr   = w >> 1, wc = w & 1;
    const int m_base = blockIdx.x * 128;
    const int n_base = blockIdx.y * 128;
    const int tb   = m_base & 1023;
    const int lrr  = lane >> 2;
    const int lj   = lane & 3;

    f32x4 acc[4][4];
#pragma unroll
    for (int m = 0; m < 4; ++m)
#pragma unroll
        for (int n = 0; n < 4; ++n) acc[m][n] = (f32x4){0.f, 0.f, 0.f, 0.f};

    for (int kc = 0; kc < K; kc += 32) {
        __syncthreads();
        for (int c = w; c < 9; c += 4) {
            const int i    = c * 16 + lrr;
            const int jc   = lj ^ SKEY(i);
            const int trow = tb + i - 8;
            const int c0   = kc + jc * 8;
            const void* src;
            if ((unsigned)trow < 1024u) {
                const int g = m_base - 8 + i;
                src = (c0 < split) ? (const void*)(A1 + (size_t)g * lda + c0)
                                   : (const void*)(A2 + (size_t)g * lda + (c0 - split));
            } else {
                src = (const void*)(zb + jc * 8);
            }
            gload16(src, (void*)&As[c * 512]);
        }
        for (int cb = w; cb < NTAPS * 8; cb += 4) {
            const int tap = cb >> 3, sub = cb & 7;
            const int r   = sub * 16 + lrr;
            const int jc  = lj ^ SKEY(r);
            gload16((const void*)(Bw + ((size_t)tap * N + n_base + r) * K + kc + jc * 8),
                    (void*)&Bs[cb * 512]);
        }
        __syncthreads();

#pragma unroll
        for (int tap = 0; tap < NTAPS; ++tap) {
            const int off = (tap == 0) ? o0 : (tap == 1) ? o1 : o2;
            short8 a[4], b[4];
#pragma unroll
            for (int m = 0; m < 4; ++m) {
                const int i = 8 + off + wr * 64 + m * 16 + (lane & 15);
                a[m] = *(const short8*)&As[i * 32 + (((lane >> 4) ^ SKEY(i)) * 8)];
            }
#pragma unroll
            for (int n = 0; n < 4; ++n) {
                const int r = wc * 64 + n * 16 + (lane & 15);
                b[n] = *(const short8*)&Bs[tap * 4096 + r * 32 + (((lane >> 4) ^ SKEY(r)) * 8)];
            }
#pragma unroll
            for (int m = 0; m < 4; ++m)
#pragma unroll
                for (int n = 0; n < 4; ++n)
                    acc[m][n] = __builtin_amdgcn_mfma_f32_16x16x32_bf16(a[m], b[n], acc[m][n], 0, 0, 0);
        }
    }

#pragma unroll
    for (int m = 0; m < 4; ++m) {
#pragma unroll
        for (int n = 0; n < 4; ++n) {
#pragma unroll
            for (int j = 0; j < 4; ++j) {
                const int row = m_base + wr * 64 + m * 16 + (lane >> 4) * 4 + j;
                const int col = n_base + wc * 64 + n * 16 + (lane & 15);
                float v = acc[m][n][j];
                if (bias) v += bias[col];
                const size_t idx = (size_t)row * ldc + col;
                if (EPI == 1) v = fmaxf(v, 0.f);
                if (EPI == 2) {
                    v = fmaxf(v, 0.f);
                    const float g  = bnp[col];
                    const float be = bnp[N + col];
                    const float mu = bnp[2 * N + col];
                    const float va = bnp[3 * N + col];
                    v = g * (v - mu) * rsqrtf(va + 1e-5f) + be;
                }
                if (Cf) Cf[idx] = v;
                if (Cb) Cb[idx] = __float2bfloat16(v);
            }
        }
    }
}

// ---------------------------------------------------------------------------
// 256x128-tile halo conv GEMM, 8 waves (4m x 2n, wave tile 64x64) — cw6.
// ---------------------------------------------------------------------------
template<int NTAPS>
__global__ __launch_bounds__(512, 4)
void cgemm2(const __hip_bfloat16* __restrict__ A1, const __hip_bfloat16* __restrict__ A2,
            int split, int lda,
            const __hip_bfloat16* __restrict__ Bw, const float* __restrict__ bias,
            float* __restrict__ Cf, __hip_bfloat16* __restrict__ Cb, int ldc,
            int N, int K,
            int o0, int o1, int o2,
            const float* __restrict__ bnp,
            const __hip_bfloat16* __restrict__ zb)
{
    __shared__ __align__(16) short As[272 * 32];
    __shared__ __align__(16) short Bs[NTAPS * 128 * 32];

    const int tid  = threadIdx.x;
    const int w    = tid >> 6;
    const int lane = tid & 63;
    const int wr   = w >> 1, wc = w & 1;      // 4 x 2 waves
    const int m_base = blockIdx.x * 256;
    const int n_base = blockIdx.y * 128;
    const int tb   = m_base & 1023;
    const int lrr  = lane >> 2;
    const int lj   = lane & 3;

    f32x4 acc[4][4];
#pragma unroll
    for (int m = 0; m < 4; ++m)
#pragma unroll
        for (int n = 0; n < 4; ++n) acc[m][n] = (f32x4){0.f, 0.f, 0.f, 0.f};

    for (int kc = 0; kc < K; kc += 32) {
        __syncthreads();
        for (int c = w; c < 17; c += 8) {
            const int i    = c * 16 + lrr;
            const int jc   = lj ^ SKEY(i);
            const int trow = tb + i - 8;
            const int c0   = kc + jc * 8;
            const void* src;
            if ((unsigned)trow < 1024u) {
                const int g = m_base - 8 + i;
                src = (c0 < split) ? (const void*)(A1 + (size_t)g * lda + c0)
                                   : (const void*)(A2 + (size_t)g * lda + (c0 - split));
            } else {
                src = (const void*)(zb + jc * 8);
            }
            gload16(src, (void*)&As[c * 512]);
        }
        for (int cb = w; cb < NTAPS * 8; cb += 8) {
            const int tap = cb >> 3, sub = cb & 7;
            const int r   = sub * 16 + lrr;
            const int jc  = lj ^ SKEY(r);
            gload16((const void*)(Bw + ((size_t)tap * N + n_base + r) * K + kc + jc * 8),
                    (void*)&Bs[cb * 512]);
        }
        __syncthreads();

#pragma unroll
        for (int tap = 0; tap < NTAPS; ++tap) {
            const int off = (tap == 0) ? o0 : (tap == 1) ? o1 : o2;
            short8 a[4], b[4];
#pragma unroll
            for (int m = 0; m < 4; ++m) {
                const int i = 8 + off + wr * 64 + m * 16 + (lane & 15);
                a[m] = *(const short8*)&As[i * 32 + (((lane >> 4) ^ SKEY(i)) * 8)];
            }
#pragma unroll
            for (int n = 0; n < 4; ++n) {
                const int r = wc * 64 + n * 16 + (lane & 15);
                b[n] = *(const short8*)&Bs[tap * 4096 + r * 32 + (((lane >> 4) ^ SKEY(r)) * 8)];
            }
#pragma unroll
            for (int m = 0; m < 4; ++m)
#pragma unroll
                for (int n = 0; n < 4; ++n)
                    acc[m][n] = __builtin_amdgcn_mfma_f32_16x16x32_bf16(a[m], b[n], acc[m][n], 0, 0, 0);
        }
    }

#pragma unroll
    for (int m = 0; m < 4; ++m) {
#pragma unroll
        for (int n = 0; n < 4; ++n) {
#pragma unroll
            for (int j = 0; j < 4; ++j) {
                const int row = m_base + wr * 64 + m * 16 + (lane >> 4) * 4 + j;
                const int col = n_base + wc * 64 + n * 16 + (lane & 15);
                float v = acc[m][n][j];
                if (bias) v += bias[col];
                v = fmaxf(v, 0.f);
                const float g  = bnp[col];
                const float be = bnp[N + col];
                const float mu = bnp[2 * N + col];
                const float va = bnp[3 * N + col];
                v = g * (v - mu) * rsqrtf(va + 1e-5f) + be;
                const size_t idx = (size_t)row * ldc + col;
                if (Cf) Cf[idx] = v;
                if (Cb) Cb[idx] = __float2bfloat16(v);
            }
        }
    }
}

// ---------------------------------------------------------------------------
// Fused 5-branch conv (4 dilated + conv5), 256x128 tile, 8 waves,
// blockIdx.z = branch.  bn==nullptr => plain relu (conv5).
// ---------------------------------------------------------------------------
struct BrP {
    const __hip_bfloat16* W;
    const float* bias;
    const float* bn;
    __hip_bfloat16* out;
    int ntaps, wti;
    int o0, o1, o2, o3, o4;
};
struct BrPs { BrP p[5]; };

__global__ __launch_bounds__(512, 4)
void bgemm(const __hip_bfloat16* __restrict__ A, BrPs ps,
           const float* __restrict__ wts,
           const __hip_bfloat16* __restrict__ zb)
{
    __shared__ __align__(16) short As[272 * 32];
    __shared__ __align__(16) short Bs[5 * 128 * 32];

    const int tid  = threadIdx.x;
    const int w    = tid >> 6;
    const int lane = tid & 63;
    const int wr   = w >> 1, wc = w & 1;      // 4 x 2 waves
    const int m_base = blockIdx.x * 256;
    const int n_base = blockIdx.y * 128;
    const int z    = blockIdx.z;
    const BrP p    = ps.p[z];
    const int tb   = m_base & 1023;
    const int lrr  = lane >> 2;
    const int lj   = lane & 3;
    const int ntaps = p.ntaps;

    f32x4 acc[4][4];
#pragma unroll
    for (int m = 0; m < 4; ++m)
#pragma unroll
        for (int n = 0; n < 4; ++n) acc[m][n] = (f32x4){0.f, 0.f, 0.f, 0.f};

    for (int kc = 0; kc < 2048; kc += 32) {
        __syncthreads();
        for (int c = w; c < 17; c += 8) {
            const int i    = c * 16 + lrr;
            const int jc   = lj ^ SKEY(i);
            const int trow = tb + i - 8;
            const void* src;
            if ((unsigned)trow < 1024u)
                src = (const void*)(A + (size_t)(m_base - 8 + i) * 2048 + kc + jc * 8);
            else
                src = (const void*)(zb + jc * 8);
            gload16(src, (void*)&As[c * 512]);
        }
        for (int cb = w; cb < ntaps * 8; cb += 8) {
            const int tap = cb >> 3, sub = cb & 7;
            const int r   = sub * 16 + lrr;
            const int jc  = lj ^ SKEY(r);
            gload16((const void*)(p.W + ((size_t)tap * 512 + n_base + r) * 2048 + kc + jc * 8),
                    (void*)&Bs[cb * 512]);
        }
        __syncthreads();

#pragma unroll 5
        for (int tap = 0; tap < ntaps; ++tap) {
            const int off = (tap == 0) ? p.o0 : (tap == 1) ? p.o1 : (tap == 2) ? p.o2
                          : (tap == 3) ? p.o3 : p.o4;
            short8 a[4], b[4];
#pragma unroll
            for (int m = 0; m < 4; ++m) {
                const int i = 8 + off + wr * 64 + m * 16 + (lane & 15);
                a[m] = *(const short8*)&As[i * 32 + (((lane >> 4) ^ SKEY(i)) * 8)];
            }
#pragma unroll
            for (int n = 0; n < 4; ++n) {
                const int r = wc * 64 + n * 16 + (lane & 15);
                b[n] = *(const short8*)&Bs[tap * 4096 + r * 32 + (((lane >> 4) ^ SKEY(r)) * 8)];
            }
#pragma unroll
            for (int m = 0; m < 4; ++m)
#pragma unroll
                for (int n = 0; n < 4; ++n)
                    acc[m][n] = __builtin_amdgcn_mfma_f32_16x16x32_bf16(a[m], b[n], acc[m][n], 0, 0, 0);
        }
    }

    const float wz = wts[p.wti];
#pragma unroll
    for (int m = 0; m < 4; ++m) {
#pragma unroll
        for (int n = 0; n < 4; ++n) {
#pragma unroll
            for (int j = 0; j < 4; ++j) {
                const int row = m_base + wr * 64 + m * 16 + (lane >> 4) * 4 + j;
                const int col = n_base + wc * 64 + n * 16 + (lane & 15);
                float v = acc[m][n][j];
                if (p.bias) v += p.bias[col];
                v = fmaxf(v, 0.f);
                if (p.bn) {
                    const float g  = p.bn[col];
                    const float be = p.bn[512 + col];
                    const float mu = p.bn[1024 + col];
                    const float va = p.bn[1536 + col];
                    v = (g * (v - mu) * rsqrtf(va + 1e-5f) + be) * wz;
                }
                p.out[(size_t)row * 512 + col] = __float2bfloat16(v);
            }
        }
    }
}

// Sum of 4 pre-weighted bf16 buffers -> bf16
__global__ void bsum_kernel(const unsigned short* __restrict__ b0, const unsigned short* __restrict__ b1,
                            const unsigned short* __restrict__ b2, const unsigned short* __restrict__ b3,
                            unsigned short* __restrict__ o, int n8)
{
    for (int i = blockIdx.x * blockDim.x + threadIdx.x; i < n8; i += gridDim.x * blockDim.x) {
        ushort8 v0 = *(const ushort8*)(b0 + (size_t)i * 8);
        ushort8 v1 = *(const ushort8*)(b1 + (size_t)i * 8);
        ushort8 v2 = *(const ushort8*)(b2 + (size_t)i * 8);
        ushort8 v3 = *(const ushort8*)(b3 + (size_t)i * 8);
        ushort8 r;
#pragma unroll
        for (int e = 0; e < 8; ++e)
            r[e] = f2bu(bu2f(v0[e]) + bu2f(v1[e]) + bu2f(v2[e]) + bu2f(v3[e]));
        *(ushort8*)(o + (size_t)i * 8) = r;
    }
}

// LayerNorm (C=512): x = LN(x + t) * g + b; also writes bf16 copy.
__global__ __launch_bounds__(256)
void ln_kernel(float* __restrict__ x, const float* __restrict__ t,
               const float* __restrict__ g, const float* __restrict__ b,
               __hip_bfloat16* __restrict__ xb, int M)
{
    const int wave = threadIdx.x >> 6;
    const int lane = threadIdx.x & 63;
    const int row  = blockIdx.x * 4 + wave;
    if (row >= M) return;
    float* xr = x + (size_t)row * 512;
    const float* tr = t + (size_t)row * 512;
    float v[8];
    float s = 0.f, s2 = 0.f;
#pragma unroll
    for (int j = 0; j < 8; ++j) {
        float val = xr[lane * 8 + j] + tr[lane * 8 + j];
        v[j] = val; s += val; s2 += val * val;
    }
#pragma unroll
    for (int d = 1; d < 64; d <<= 1) {
        s  += __shfl_xor(s, d, 64);
        s2 += __shfl_xor(s2, d, 64);
    }
    const float mean = s * (1.f / 512.f);
    const float var  = s2 * (1.f / 512.f) - mean * mean;
    const float rstd = rsqrtf(var + 1e-5f);
#pragma unroll
    for (int j = 0; j < 8; ++j) {
        const int c = lane * 8 + j;
        const float o = (v[j] - mean) * rstd * g[c] + b[c];
        xr[c] = o;
        xb[(size_t)row * 512 + c] = __float2bfloat16(o);
    }
}

// ---------------------------------------------------------------------------
// MFMA flash attention (bf16 in/out).  setprio kept (m191: attn-positive).
// ---------------------------------------------------------------------------
__global__ __launch_bounds__(256)
void mattn(const __hip_bfloat16* __restrict__ qkv, __hip_bfloat16* __restrict__ o)
{
    __shared__ __align__(16) short Ks[4096];
    __shared__ __align__(16) short Vt[4096];
    __shared__ __align__(16) short Pl[8192];

    const int tid  = threadIdx.x;
    const int w    = tid >> 6;
    const int lane = tid & 63;
    const int g    = lane >> 4;
    const int li   = lane & 15;
    const int b    = blockIdx.x >> 3;
    const int h    = blockIdx.x & 7;
    const int qb   = blockIdx.y * 128 + w * 32;

    const short* qkvs = (const short*)qkv;

    short8 qf[2][2];
#pragma unroll
    for (int m = 0; m < 2; ++m)
#pragma unroll
        for (int ks = 0; ks < 2; ++ks)
            qf[m][ks] = *(const short8*)(qkvs +
                (size_t)(b * 1024 + qb + m * 16 + li) * 1536 + h * 64 + ks * 32 + g * 8);

    f32x4 Oa[2][4];
    float mr[2][4], lr[2][4];
#pragma unroll
    for (int m = 0; m < 2; ++m)
#pragma unroll
        for (int j = 0; j < 4; ++j) { mr[m][j] = -1e30f; lr[m][j] = 0.f; }
#pragma unroll
    for (int m = 0; m < 2; ++m)
#pragma unroll
        for (int n = 0; n < 4; ++n) Oa[m][n] = (f32x4){0.f, 0.f, 0.f, 0.f};

    const int sr = tid >> 2;
    const int sc = (tid & 3) * 16;

    for (int kt = 0; kt < 16; ++kt) {
        __syncthreads();
        const short* kr = qkvs + (size_t)(b * 1024 + kt * 64 + sr) * 1536 + 512 + h * 64 + sc;
        short8 k0 = *(const short8*)kr;
        short8 k1 = *(const short8*)(kr + 8);
        short8 v0 = *(const short8*)(kr + 512);
        short8 v1 = *(const short8*)(kr + 520);
        const int swr = (sr & 7) << 4;
        *(short8*)&Ks[(sr * 128 + ((sc * 2) ^ swr)) >> 1] = k0;
        *(short8*)&Ks[(sr * 128 + ((sc * 2 + 16) ^ swr)) >> 1] = k1;
#pragma unroll
        for (int e = 0; e < 8; ++e) {
            const int d = sc + e;
            Vt[(d * 128 + ((sr * 2) ^ ((d & 7) << 4))) >> 1] = v0[e];
        }
#pragma unroll
        for (int e = 0; e < 8; ++e) {
            const int d = sc + 8 + e;
            Vt[(d * 128 + ((sr * 2) ^ ((d & 7) << 4))) >> 1] = v1[e];
        }
        __syncthreads();

        short8 kf[4][2], vf[4][2];
#pragma unroll
        for (int n = 0; n < 4; ++n) {
            const int r  = n * 16 + li;
            const int sw = (r & 7) << 4;
#pragma unroll
            for (int ks = 0; ks < 2; ++ks) {
                const int cb = ks * 64 + g * 16;
                kf[n][ks] = *(const short8*)&Ks[(r * 128 + (cb ^ sw)) >> 1];
                vf[n][ks] = *(const short8*)&Vt[(r * 128 + (cb ^ sw)) >> 1];
            }
        }

        f32x4 s[2][4];
#pragma unroll
        for (int m = 0; m < 2; ++m)
#pragma unroll
            for (int n = 0; n < 4; ++n) s[m][n] = (f32x4){0.f, 0.f, 0.f, 0.f};
        __builtin_amdgcn_s_setprio(1);
#pragma unroll
        for (int m = 0; m < 2; ++m)
#pragma unroll
            for (int n = 0; n < 4; ++n)
#pragma unroll
                for (int ks = 0; ks < 2; ++ks)
                    s[m][n] = __builtin_amdgcn_mfma_f32_16x16x32_bf16(qf[m][ks], kf[n][ks], s[m][n], 0, 0, 0);
        __builtin_amdgcn_s_setprio(0);

#pragma unroll
        for (int m = 0; m < 2; ++m) {
            float cc[4];
#pragma unroll
            for (int j = 0; j < 4; ++j) {
                float rm = fmaxf(fmaxf(s[m][0][j], s[m][1][j]), fmaxf(s[m][2][j], s[m][3][j]));
                rm *= 0.125f;
#pragma unroll
                for (int d = 1; d < 16; d <<= 1) rm = fmaxf(rm, __shfl_xor(rm, d, 64));
                const float mn = fmaxf(mr[m][j], rm);
                cc[j] = __expf(mr[m][j] - mn);
                mr[m][j] = mn;
            }
            float rs[4] = {0.f, 0.f, 0.f, 0.f};
#pragma unroll
            for (int n = 0; n < 4; ++n)
#pragma unroll
                for (int j = 0; j < 4; ++j) {
                    const float pv = __expf(s[m][n][j] * 0.125f - mr[m][j]);
                    rs[j] += pv;
                    const int r  = m * 16 + g * 4 + j;
                    const int cb = (n * 16 + li) * 2;
                    Pl[(w * 4096 + r * 128 + (cb ^ ((r & 7) << 4))) >> 1] = (short)f2bu(pv);
                }
#pragma unroll
            for (int j = 0; j < 4; ++j) {
#pragma unroll
                for (int d = 1; d < 16; d <<= 1) rs[j] += __shfl_xor(rs[j], d, 64);
                lr[m][j] = lr[m][j] * cc[j] + rs[j];
#pragma unroll
                for (int n = 0; n < 4; ++n) Oa[m][n][j] *= cc[j];
            }
        }
        __syncthreads();

        short8 pa[2][2];
#pragma unroll
        for (int m = 0; m < 2; ++m) {
            const int r  = m * 16 + li;
            const int sw = (r & 7) << 4;
#pragma unroll
            for (int ks = 0; ks < 2; ++ks) {
                const int cb = ks * 64 + g * 16;
                pa[m][ks] = *(const short8*)&Pl[(w * 4096 + r * 128 + (cb ^ sw)) >> 1];
            }
        }
        __builtin_amdgcn_s_setprio(1);
#pragma unroll
        for (int m = 0; m < 2; ++m)
#pragma unroll
            for (int n = 0; n < 4; ++n)
#pragma unroll
                for (int ks = 0; ks < 2; ++ks)
                    Oa[m][n] = __builtin_amdgcn_mfma_f32_16x16x32_bf16(pa[m][ks], vf[n][ks], Oa[m][n], 0, 0, 0);
        __builtin_amdgcn_s_setprio(0);
    }

#pragma unroll
    for (int m = 0; m < 2; ++m)
#pragma unroll
        for (int j = 0; j < 4; ++j) {
            const float inv = 1.f / lr[m][j];
            const size_t row = (size_t)(b * 1024 + qb + m * 16 + g * 4 + j);
#pragma unroll
            for (int n = 0; n < 4; ++n)
                o[row * 512 + h * 64 + n * 16 + li] = __float2bfloat16(Oa[m][n][j] * inv);
        }
}

// ---------------------------------------------------------------------------

extern "C" void kernel_launch(void* const* d_in, const int* in_sizes, int n_in,
                              void* d_out, int out_size, void* d_ws, size_t ws_size,
                              hipStream_t stream)
{
    const float* x       = (const float*)d_in[0];
    const float* wts     = (const float*)d_in[1];
    const float* cw1     = (const float*)d_in[2];
    const float* cb1     = (const float*)d_in[3];
    const float* bn1     = (const float*)d_in[4];
    const float* cw2     = (const float*)d_in[5];
    const float* cb2     = (const float*)d_in[6];
    const float* bn2     = (const float*)d_in[7];
    const float* cw3     = (const float*)d_in[8];
    const float* cb3     = (const float*)d_in[9];
    const float* bn3     = (const float*)d_in[10];
    const float* cw4     = (const float*)d_in[11];
    const float* cb4     = (const float*)d_in[12];
    const float* bn4     = (const float*)d_in[13];
    const float* cw5     = (const float*)d_in[14];
    const float* tcw_in  = (const float*)d_in[15];
    const float* tcb_in  = (const float*)d_in[16];
    const float* t_in_w  = (const float*)d_in[17];
    const float* t_in_b  = (const float*)d_in[18];
    const float* t_out_w = (const float*)d_in[19];
    const float* t_out_b = (const float*)d_in[20];
    const float* ln1_g   = (const float*)d_in[21];
    const float* ln1_b   = (const float*)d_in[22];
    const float* ff_w1   = (const float*)d_in[23];
    const float* ff_b1   = (const float*)d_in[24];
    const float* ff_w2   = (const float*)d_in[25];
    const float* ff_b2   = (const float*)d_in[26];
    const float* ln2_g   = (const float*)d_in[27];
    const float* ln2_b   = (const float*)d_in[28];
    const float* tcw_out = (const float*)d_in[29];
    const float* tcb_out = (const float*)d_in[30];
    const float* cw6     = (const float*)d_in[31];
    const float* bn6     = (const float*)d_in[32];
    const float* bw1     = (const float*)d_in[33];
    const float* bb1     = (const float*)d_in[34];
    const float* bw2     = (const float*)d_in[35];
    const float* bb2     = (const float*)d_in[36];
    const float* bw3     = (const float*)d_in[37];
    const float* bb3     = (const float*)d_in[38];
    float* out = (float*)d_out;

    // -------- workspace map --------
    const size_t HMB = 524288;
    char* ws = (char*)d_ws;
    auto BF = [&](double mb) { return (__hip_bfloat16*)(ws + (size_t)(mb * 2) * HMB); };
    auto FP = [&](double mb) { return (float*)(ws + (size_t)(mb * 2) * HMB); };

    __hip_bfloat16* xb    = BF(0);       // 0-32    x bf16; dead after bgemm
    float*          h7    = FP(0);       // 0-64    cw6 out fp32 (late phase)
    __hip_bfloat16* bigqb = BF(32);      // 32-56   qkv bf16 (transformer)
    __hip_bfloat16* wc1   = BF(32);      // 32-38.5 early conv weights (dead pre-qkv)
    __hip_bfloat16* wc2   = BF(39);      // 39-45.5
    __hip_bfloat16* wc3   = BF(46);      // 46-52.5
    __hip_bfloat16* wc4   = BF(53);      // 53-63.5
    __hip_bfloat16* wc5   = BF(64);      // 64-66.1
    __hip_bfloat16* wti0  = BF(66.5);
    __hip_bfloat16* wti1  = BF(68);
    __hip_bfloat16* wto0  = BF(69.5);
    __hip_bfloat16* wto1  = BF(70);
    __hip_bfloat16* wf10  = BF(70.5);
    __hip_bfloat16* wf11  = BF(72.5);
    __hip_bfloat16* wf20  = BF(74.5);
    __hip_bfloat16* wf21  = BF(76.5);
    __hip_bfloat16* wtci  = BF(78.5);
    __hip_bfloat16* wtco  = BF(79);
    __hip_bfloat16* bigb  = BF(80);      // 80-112  ff hidden bf16
    __hip_bfloat16* h7b   = BF(80);      // 80-112  h7 bf16 (after ff done)
    __hip_bfloat16* br0   = BF(112);     // branch outputs bf16
    __hip_bfloat16* br1   = BF(120);
    __hip_bfloat16* br2   = BF(128);
    __hip_bfloat16* br3   = BF(136);
    float*          tmp   = FP(112);     // LN residual fp32 (after bsum)
    float*          xtf   = FP(128);     // transformer fp32 stream (after bsum)
    __hip_bfloat16* outdb = BF(144);     // branch sum; later bw1 out
    __hip_bfloat16* wc6   = BF(152);     // 152-164.6
    __hip_bfloat16* wtb1  = BF(165);     // 165-167
    __hip_bfloat16* wtb2  = BF(167.5);   // 167.5-169  (3-tap = 1.5 MB)
    __hip_bfloat16* wtb3  = BF(169);     // 169-171
    __hip_bfloat16* tmpb  = BF(171);     // conv5 out / attn out / bw2 out
    __hip_bfloat16* atnb  = BF(171);
    __hip_bfloat16* xtfb  = BF(179);
    __hip_bfloat16* zb    = BF(188);     // zero mask row

    const int M = 8192;
    dim3 blk(256);
    dim3 blk2(512);

    auto mg = [&](int bm, int epi, const __hip_bfloat16* A, int lda,
                  const __hip_bfloat16* Bw, const float* bias,
                  float* Cf, __hip_bfloat16* Cb, int ldc, int N, int K,
                  const float* r1, int ldr, const float* r2) {
        dim3 grid(M / bm, N / 128);
#define LAU(BMV, EPIV) mgemm<BMV, EPIV><<<grid, blk, 0, stream>>>(A, lda, Bw, bias, Cf, Cb, ldc, N, K, r1, ldr, r2)
        if (bm == 64) {
            switch (epi) { case 0: LAU(64, 0); break; case 1: LAU(64, 1); break;
                           default: LAU(64, 3); }
        } else {
            switch (epi) { case 0: LAU(128, 0); break; case 1: LAU(128, 1); break;
                           default: LAU(128, 3); }
        }
#undef LAU
    };

    auto pg = [&](int epi, const __hip_bfloat16* A, int lda,
                  const __hip_bfloat16* Bw, const float* bias,
                  float* Cf, __hip_bfloat16* Cb, int ldc, int N, int K,
                  const float* r1, int ldr, const float* r2) {
        dim3 grid(M / 256, N / 128);
        switch (epi) {
        case 0: pgemm<0><<<grid, blk2, 0, stream>>>(A, lda, Bw, bias, Cf, Cb, ldc, N, K, r1, ldr, r2); break;
        case 1: pgemm<1><<<grid, blk2, 0, stream>>>(A, lda, Bw, bias, Cf, Cb, ldc, N, K, r1, ldr, r2); break;
        default: pgemm<3><<<grid, blk2, 0, stream>>>(A, lda, Bw, bias, Cf, Cb, ldc, N, K, r1, ldr, r2); break;
        }
    };

    // ---- prologue ----
    hipMemsetAsync(zb, 0, 8192, stream);
    cast_kernel<<<dim3(2048), blk, 0, stream>>>(x, (unsigned short*)xb, M * 2048 / 8);

    WJobs jobs{};
    jobs.n = 19;
    jobs.j[0]  = {cw1,                   (unsigned short*)wc1, 512, 2048, 3};
    jobs.j[1]  = {cw2,                   (unsigned short*)wc2, 512, 2048, 3};
    jobs.j[2]  = {cw3,                   (unsigned short*)wc3, 512, 2048, 3};
    jobs.j[3]  = {cw4,                   (unsigned short*)wc4, 512, 2048, 5};
    jobs.j[4]  = {cw5,                   (unsigned short*)wc5, 512, 2048, 1};
    jobs.j[5]  = {t_in_w,                (unsigned short*)wti0, 1536, 512, 1};
    jobs.j[6]  = {t_in_w + 1536 * 512,   (unsigned short*)wti1, 1536, 512, 1};
    jobs.j[7]  = {t_out_w,               (unsigned short*)wto0, 512, 512, 1};
    jobs.j[8]  = {t_out_w + 512 * 512,   (unsigned short*)wto1, 512, 512, 1};
    jobs.j[9]  = {ff_w1,                 (unsigned short*)wf10, 2048, 512, 1};
    jobs.j[10] = {ff_w1 + 2048 * 512,    (unsigned short*)wf11, 2048, 512, 1};
    jobs.j[11] = {ff_w2,                 (unsigned short*)wf20, 512, 2048, 1};
    jobs.j[12] = {ff_w2 + 512 * 2048,    (unsigned short*)wf21, 512, 2048, 1};
    jobs.j[13] = {tcw_in,                (unsigned short*)wtci, 512, 512, 1};
    jobs.j[14] = {tcw_out,               (unsigned short*)wtco, 512, 512, 1};
    jobs.j[15] = {cw6,                   (unsigned short*)wc6, 2048, 1024, 3};
    jobs.j[16] = {bw1,                   (unsigned short*)wtb1, 512, 2048, 1};
    jobs.j[17] = {bw2,                   (unsigned short*)wtb2, 512, 512, 3};
    jobs.j[18] = {bw3,                   (unsigned short*)wtb3, 2048, 512, 1};
    wtrans_multi<<<dim3(2048), blk, 0, stream>>>(jobs);

    // ---- fused 5-branch convs (4 dilated + conv5), single launch ----
    BrPs bp{};
    bp.p[0] = {wc1, cb1, bn1, br0, 3, 0, -1, 0, 1, 0, 0};
    bp.p[1] = {wc2, cb2, bn2, br1, 3, 1, -2, 0, 2, 0, 0};
    bp.p[2] = {wc3, cb3, bn3, br2, 3, 2, -4, 0, 4, 0, 0};
    bp.p[3] = {wc4, cb4, bn4, br3, 5, 3, -8, -4, 0, 4, 8};
    bp.p[4] = {wc5, nullptr, nullptr, tmpb, 1, 0, 0, 0, 0, 0, 0};
    bgemm<<<dim3(M / 256, 4, 5), blk2, 0, stream>>>(xb, bp, wts, zb);
    bsum_kernel<<<dim3(2048), blk, 0, stream>>>((const unsigned short*)br0, (const unsigned short*)br1,
                                                (const unsigned short*)br2, (const unsigned short*)br3,
                                                (unsigned short*)outdb, M * 512 / 8);

    // ---- tcw_in -> xtf (+xtfb) ----
    mg(64, 0, tmpb, 512, wtci, tcb_in, xtf, xtfb, 512, 512, 512, nullptr, 0, nullptr);

    // ---- transformer layers ----
    for (int l = 0; l < 2; ++l) {
        const __hip_bfloat16* wi = l ? wti1 : wti0;
        const __hip_bfloat16* wo = l ? wto1 : wto0;
        const __hip_bfloat16* w1 = l ? wf11 : wf10;
        const __hip_bfloat16* w2 = l ? wf21 : wf20;
        pg(0, xtfb, 512, wi, t_in_b + l * 1536, nullptr, bigqb, 1536, 1536, 512,
           nullptr, 0, nullptr);
        mattn<<<dim3(64, 8), blk, 0, stream>>>(bigqb, atnb);
        mg(64, 0, atnb, 512, wo, t_out_b + l * 512, tmp, nullptr, 512, 512, 512,
           nullptr, 0, nullptr);
        ln_kernel<<<dim3(M / 4), blk, 0, stream>>>(xtf, tmp, ln1_g + l * 512, ln1_b + l * 512, xtfb, M);
        pg(1, xtfb, 512, w1, ff_b1 + l * 2048, nullptr, bigb, 2048, 2048, 512,
           nullptr, 0, nullptr);
        mg(64, 0, bigb, 2048, w2, ff_b2 + l * 512, tmp, nullptr, 512, 512, 2048,
           nullptr, 0, nullptr);
        ln_kernel<<<dim3(M / 4), blk, 0, stream>>>(xtf, tmp, ln2_g + l * 512, ln2_b + l * 512, xtfb, M);
    }

    // ---- tcw_out -> atnb (bf16 only) ----
    mg(64, 0, xtfb, 512, wtco, tcb_out, nullptr, atnb, 512, 512, 512, nullptr, 0, nullptr);

    // ---- cw6: concat(outdb, atnb) k=3 -> BN6 -> h7 (fp32 + bf16), 256-tile 8-wave ----
    cgemm2<3><<<dim3(M / 256, 16), blk2, 0, stream>>>(outdb, atnb, 512, 512, wc6, nullptr,
        h7, h7b, 2048, 2048, 1024, -1, 0, 1, bn6, zb);

    // ---- bottleneck ----
    mg(64, 1, h7b, 2048, wtb1, bb1, nullptr, outdb, 512, 512, 2048, nullptr, 0, nullptr);
    cgemm<3, 1><<<dim3(M / 128, 4), blk, 0, stream>>>(outdb, outdb, 4096, 512, wtb2, bb2,
        nullptr, tmpb, 512, 512, 512, -1, 0, 1, nullptr, zb);
    pg(3, tmpb, 512, wtb3, bb3, out, nullptr, 2048, 2048, 512, h7, 2048, x);

    (void)in_sizes; (void)n_in; (void)out_size; (void)ws_size;
}